// Round 1
// baseline (798.483 us; speedup 1.0000x reference)
//
#include <hip/hip_runtime.h>
#include <hip/hip_bf16.h>
#include <hip/hip_fp16.h>

typedef _Float16 half8 __attribute__((ext_vector_type(8)));
typedef _Float16 half4v __attribute__((ext_vector_type(4)));
typedef float f4 __attribute__((ext_vector_type(4)));
typedef short short8 __attribute__((ext_vector_type(8)));

#define P_SZ 4096
#define CH 256      // hidden (qk) channels
#define CIN 512     // input channels
#define CV 512      // value channels

__device__ __forceinline__ unsigned short f2bf(float f) {
  unsigned u = __float_as_uint(f);
  unsigned r = u + 0x7fffu + ((u >> 16) & 1u);
  return (unsigned short)(r >> 16);
}
__device__ __forceinline__ float bf2f(unsigned short h) {
  return __uint_as_float(((unsigned)h) << 16);
}

// ---------------- V convert: fp32 -> fp16, layout kept [b][c][p] ----------------
__global__ __launch_bounds__(256) void vconv_kernel(const float* __restrict__ in,
                                                    _Float16* __restrict__ outv) {
  const size_t i = (size_t)blockIdx.x * 256 + threadIdx.x;
  const f4 x = ((const f4*)in)[i];
  half4v h;
  h[0] = (_Float16)x[0]; h[1] = (_Float16)x[1];
  h[2] = (_Float16)x[2]; h[3] = (_Float16)x[3];
  ((half4v*)outv)[i] = h;
}

// ---------------- Projection: out[b][p][o] = sum_c W[o][c] * X[b][c][p] + bias[o]
// split-bf16 (hi/lo, 3 MFMA passes) for ~fp32 accuracy, result stored fp16.
__global__ __launch_bounds__(512) void proj_kernel(
    const float* __restrict__ Xq, const float* __restrict__ Wq, const float* __restrict__ bq,
    const float* __restrict__ Xk, const float* __restrict__ Wk, const float* __restrict__ bk,
    _Float16* __restrict__ Qout, _Float16* __restrict__ Kout) {
  const int which = blockIdx.z;
  const float* __restrict__ X = which ? Xk : Xq;
  const float* __restrict__ W = which ? Wk : Wq;
  const float* __restrict__ bias = which ? bk : bq;
  _Float16* __restrict__ out = which ? Kout : Qout;

  const int b = blockIdx.y;
  const int p0 = blockIdx.x * 64;
  const int tid = threadIdx.x;
  const int w = tid >> 6, l = tid & 63;
  const int wp = w >> 2, wo = w & 3;       // 2 p-halves x 4 o-groups
  const int lr = l & 15, lg = l >> 4;

  const float* __restrict__ Xb = X + (size_t)b * CIN * P_SZ;

  f4 acc[2][4];
  #pragma unroll
  for (int m = 0; m < 2; ++m)
    #pragma unroll
    for (int n = 0; n < 4; ++n) acc[m][n] = (f4){0.f, 0.f, 0.f, 0.f};

  const int prow0 = p0 + wp * 32 + lr;

  #pragma unroll 1
  for (int kc = 0; kc < CIN; kc += 32) {
    // A = X^T fragments: row(m)=p (lane&15), k=c (lg*8+i), strided global reads
    short8 ah[2], al[2];
    #pragma unroll
    for (int m = 0; m < 2; ++m) {
      const float* xp = Xb + (size_t)(kc + lg * 8) * P_SZ + (prow0 + m * 16);
      #pragma unroll
      for (int i = 0; i < 8; ++i) {
        float xv = xp[(size_t)i * P_SZ];
        unsigned short h = f2bf(xv);
        ah[m][i] = (short)h;
        al[m][i] = (short)f2bf(xv - bf2f(h));
      }
    }
    // B = W^T fragments: n=o (lane&15), k=c contiguous in W rows
    short8 bh[4], bl[4];
    #pragma unroll
    for (int n = 0; n < 4; ++n) {
      const float* wr = W + (size_t)(wo * 64 + n * 16 + lr) * CIN + kc + lg * 8;
      #pragma unroll
      for (int i = 0; i < 8; ++i) {
        float wv = wr[i];
        unsigned short h = f2bf(wv);
        bh[n][i] = (short)h;
        bl[n][i] = (short)f2bf(wv - bf2f(h));
      }
    }
    #pragma unroll
    for (int m = 0; m < 2; ++m)
      #pragma unroll
      for (int n = 0; n < 4; ++n) {
        acc[m][n] = __builtin_amdgcn_mfma_f32_16x16x32_bf16(ah[m], bh[n], acc[m][n], 0, 0, 0);
        acc[m][n] = __builtin_amdgcn_mfma_f32_16x16x32_bf16(ah[m], bl[n], acc[m][n], 0, 0, 0);
        acc[m][n] = __builtin_amdgcn_mfma_f32_16x16x32_bf16(al[m], bh[n], acc[m][n], 0, 0, 0);
      }
  }

  #pragma unroll
  for (int n = 0; n < 4; ++n) {
    const int o = wo * 64 + n * 16 + lr;
    const float bv = bias[o];
    #pragma unroll
    for (int m = 0; m < 2; ++m) {
      #pragma unroll
      for (int j = 0; j < 4; ++j) {
        const int p = p0 + wp * 32 + m * 16 + lg * 4 + j;
        out[((size_t)b * P_SZ + p) * CH + o] = (_Float16)(acc[m][n][j] + bv);
      }
    }
  }
}

// ---------------- Fused flash attention ----------------
// block: (b, 32 queries). 8 waves. Q frags in regs; K/V frags direct from global
// (L2/L3-resident); S via LDS; online softmax; P~ via XOR-swizzled LDS.
__global__ __launch_bounds__(512) void attn_kernel(
    const _Float16* __restrict__ Qg, const _Float16* __restrict__ Kg,
    const _Float16* __restrict__ Vg, float* __restrict__ Og) {
  __shared__ float s_lds[32][68];       // padded: 2-way max on writes (free)
  __shared__ _Float16 p_lds[32 * 64];   // XOR-swizzled rows
  __shared__ float alpha_lds[32];
  __shared__ float lsum_lds[32];

  const int b = blockIdx.y;
  const int q0 = blockIdx.x * 32;
  const int tid = threadIdx.x;
  const int w = tid >> 6, l = tid & 63;
  const int lr = l & 15, lg = l >> 4;
  const int wq = w >> 2;   // query half (16 rows)
  const int ks = w & 3;    // QK: key subtile; PV: 128-channel group

  const _Float16* __restrict__ Qb = Qg + ((size_t)b * P_SZ + q0) * CH;
  const _Float16* __restrict__ Kb = Kg + (size_t)b * P_SZ * CH;
  const _Float16* __restrict__ Vb = Vg + (size_t)b * CV * P_SZ;

  // Q fragments for this wave's 16 rows, all 256 channels: 8 x half8 = 32 VGPR
  half8 qf[8];
  {
    const _Float16* qrow = Qb + (size_t)(wq * 16 + lr) * CH + lg * 8;
    #pragma unroll
    for (int c = 0; c < 8; ++c) qf[c] = *(const half8*)(qrow + c * 32);
  }

  f4 acc[8];
  #pragma unroll
  for (int n = 0; n < 8; ++n) acc[n] = (f4){0.f, 0.f, 0.f, 0.f};

  float mrow = -1e30f, lsum = 0.f;
  const int r = w * 4 + lg;             // softmax row owned by this lane
  char* const pbase = (char*)p_lds;

  #pragma unroll 1
  for (int t = 0; t < 64; ++t) {
    const int key0 = t * 64;
    // ---- QK: wave computes S[wq*16..+16][ks*16..+16] over K=256 ----
    f4 s = (f4){0.f, 0.f, 0.f, 0.f};
    {
      const _Float16* kp = Kb + (size_t)(key0 + ks * 16 + lr) * CH + lg * 8;
      #pragma unroll
      for (int c = 0; c < 8; ++c) {
        half8 bf = *(const half8*)(kp + c * 32);
        s = __builtin_amdgcn_mfma_f32_16x16x32_f16(qf[c], bf, s, 0, 0, 0);
      }
    }
    #pragma unroll
    for (int j = 0; j < 4; ++j)
      s_lds[wq * 16 + lg * 4 + j][ks * 16 + lr] = s[j];
    __syncthreads();

    // ---- online softmax: wave handles rows w*4 + lg, 16 lanes per row ----
    f4 sv = *(const f4*)&s_lds[r][lr * 4];
    float tmax = fmaxf(fmaxf(sv[0], sv[1]), fmaxf(sv[2], sv[3]));
    #pragma unroll
    for (int off = 1; off < 16; off <<= 1) tmax = fmaxf(tmax, __shfl_xor(tmax, off));
    const float mnew = fmaxf(mrow, tmax);
    const float alpha = __expf(mrow - mnew);
    const float e0 = __expf(sv[0] - mnew), e1 = __expf(sv[1] - mnew);
    const float e2 = __expf(sv[2] - mnew), e3 = __expf(sv[3] - mnew);
    float ssum = (e0 + e1) + (e2 + e3);
    #pragma unroll
    for (int off = 1; off < 16; off <<= 1) ssum += __shfl_xor(ssum, off);
    lsum = lsum * alpha + ssum;
    mrow = mnew;
    half4v pv;
    pv[0] = (_Float16)e0; pv[1] = (_Float16)e1; pv[2] = (_Float16)e2; pv[3] = (_Float16)e3;
    *(half4v*)(pbase + (((r * 128) + lr * 8) ^ ((r & 7) << 4))) = pv;
    if (lr == 0) alpha_lds[r] = alpha;
    __syncthreads();

    // ---- PV: wave (wq, ks) -> out rows wq*16..+16, channels ks*128..+128 ----
    float aj[4];
    #pragma unroll
    for (int j = 0; j < 4; ++j) aj[j] = alpha_lds[wq * 16 + lg * 4 + j];
    #pragma unroll
    for (int n = 0; n < 8; ++n) {
      acc[n][0] *= aj[0]; acc[n][1] *= aj[1];
      acc[n][2] *= aj[2]; acc[n][3] *= aj[3];
    }
    const int prow = wq * 16 + lr;
    #pragma unroll
    for (int kk = 0; kk < 2; ++kk) {
      half8 af = *(const half8*)(pbase +
          (((prow * 128) + (kk * 32 + lg * 8) * 2) ^ ((prow & 7) << 4)));
      const _Float16* vp = Vb + (size_t)(ks * 128 + lr) * P_SZ + key0 + kk * 32 + lg * 8;
      #pragma unroll
      for (int n = 0; n < 8; ++n) {
        half8 bv = *(const half8*)(vp + (size_t)n * 16 * P_SZ);
        acc[n] = __builtin_amdgcn_mfma_f32_16x16x32_f16(af, bv, acc[n], 0, 0, 0);
      }
    }
    // no barrier needed here: next S-write is gated by the barrier after it
  }

  if (lr == 0) lsum_lds[r] = lsum;
  __syncthreads();
  float linv[4];
  #pragma unroll
  for (int j = 0; j < 4; ++j) linv[j] = 1.f / lsum_lds[wq * 16 + lg * 4 + j];
  #pragma unroll
  for (int n = 0; n < 8; ++n) {
    f4 o;
    o[0] = acc[n][0] * linv[0]; o[1] = acc[n][1] * linv[1];
    o[2] = acc[n][2] * linv[2]; o[3] = acc[n][3] * linv[3];
    const int ch = ks * 128 + n * 16 + lr;
    float* op = Og + ((size_t)b * CV + ch) * P_SZ + q0 + wq * 16 + lg * 4;
    *(f4*)op = o;
  }
}

extern "C" void kernel_launch(void* const* d_in, const int* in_sizes, int n_in,
                              void* d_out, int out_size, void* d_ws, size_t ws_size,
                              hipStream_t stream) {
  const float* x  = (const float*)d_in[0];   // query_features  [4,512,64,64]
  const float* f  = (const float*)d_in[1];   // reference_features [4,512,64,64]
  const float* Wq = (const float*)d_in[2];   // [256,512]
  const float* bq = (const float*)d_in[3];   // [256]
  const float* Wk = (const float*)d_in[4];   // [256,512]
  const float* bk = (const float*)d_in[5];   // [256]
  float* out = (float*)d_out;

  char* ws = (char*)d_ws;
  _Float16* Qf = (_Float16*)ws;                      // [4][4096][256] fp16: 8 MB
  _Float16* Kf = (_Float16*)(ws + (size_t)8 * 1024 * 1024);   // [4][4096][256]: 8 MB
  _Float16* Vf = (_Float16*)(ws + (size_t)16 * 1024 * 1024);  // [4][512][4096]: 16 MB

  // V: fp32 -> fp16 (4*512*4096 / 4 per thread = 2,097,152 threads)
  vconv_kernel<<<dim3(8192), dim3(256), 0, stream>>>(f, Vf);
  // Q and K projections (z=0: Q from x, z=1: K from f)
  proj_kernel<<<dim3(64, 4, 2), dim3(512), 0, stream>>>(x, Wq, bq, f, Wk, bk, Qf, Kf);
  // fused attention
  attn_kernel<<<dim3(128, 4), dim3(512), 0, stream>>>(Qf, Kf, Vf, out);
}

// Round 2
// 307.347 us; speedup vs baseline: 2.5980x; 2.5980x over previous
//
#include <hip/hip_runtime.h>
#include <hip/hip_bf16.h>
#include <hip/hip_fp16.h>

typedef _Float16 half8 __attribute__((ext_vector_type(8)));
typedef _Float16 half4v __attribute__((ext_vector_type(4)));
typedef float f4 __attribute__((ext_vector_type(4)));
typedef short short8 __attribute__((ext_vector_type(8)));

#define P_SZ 4096
#define CH 256      // hidden (qk) channels
#define CIN 512     // input channels
#define CV 512      // value channels
#define QBLK 64
#define KVB 32
#define NT (P_SZ / KVB)   // 128 kv tiles

__device__ __forceinline__ unsigned short f2bf(float f) {
  unsigned u = __float_as_uint(f);
  unsigned r = u + 0x7fffu + ((u >> 16) & 1u);
  return (unsigned short)(r >> 16);
}
__device__ __forceinline__ float bf2f(unsigned short h) {
  return __uint_as_float(((unsigned)h) << 16);
}

__device__ __forceinline__ void gload16(const void* g, void* l) {
  __builtin_amdgcn_global_load_lds(
      (const __attribute__((address_space(1))) unsigned int*)g,
      (__attribute__((address_space(3))) unsigned int*)l, 16, 0, 0);
}

// ---------------- V convert: fp32 -> fp16, layout kept [b][c][p] ----------------
__global__ __launch_bounds__(256) void vconv_kernel(const float* __restrict__ in,
                                                    _Float16* __restrict__ outv) {
  const size_t i = (size_t)blockIdx.x * 256 + threadIdx.x;
  const f4 x = ((const f4*)in)[i];
  half4v h;
  h[0] = (_Float16)x[0]; h[1] = (_Float16)x[1];
  h[2] = (_Float16)x[2]; h[3] = (_Float16)x[3];
  ((half4v*)outv)[i] = h;
}

// ---------------- Projection: out[b][p][o^swz] = sum_c W[o][c] * X[b][c][p] + bias[o]
// split-bf16 (hi/lo, 3 MFMA passes) for ~fp32 accuracy, result stored fp16.
// Rows are stored with a 16B-chunk XOR swizzle (o ^= (p&7)<<3) so that the attn
// kernel's linear global_load_lds staging yields bank-conflict-free ds_reads.
__global__ __launch_bounds__(512) void proj_kernel(
    const float* __restrict__ Xq, const float* __restrict__ Wq, const float* __restrict__ bq,
    const float* __restrict__ Xk, const float* __restrict__ Wk, const float* __restrict__ bk,
    _Float16* __restrict__ Qout, _Float16* __restrict__ Kout) {
  const int which = blockIdx.z;
  const float* __restrict__ X = which ? Xk : Xq;
  const float* __restrict__ W = which ? Wk : Wq;
  const float* __restrict__ bias = which ? bk : bq;
  _Float16* __restrict__ out = which ? Kout : Qout;

  const int b = blockIdx.y;
  const int p0 = blockIdx.x * 64;
  const int tid = threadIdx.x;
  const int w = tid >> 6, l = tid & 63;
  const int wp = w >> 2, wo = w & 3;       // 2 p-halves x 4 o-groups
  const int lr = l & 15, lg = l >> 4;

  const float* __restrict__ Xb = X + (size_t)b * CIN * P_SZ;

  f4 acc[2][4];
  #pragma unroll
  for (int m = 0; m < 2; ++m)
    #pragma unroll
    for (int n = 0; n < 4; ++n) acc[m][n] = (f4){0.f, 0.f, 0.f, 0.f};

  const int prow0 = p0 + wp * 32 + lr;

  #pragma unroll 1
  for (int kc = 0; kc < CIN; kc += 32) {
    short8 ah[2], al[2];
    #pragma unroll
    for (int m = 0; m < 2; ++m) {
      const float* xp = Xb + (size_t)(kc + lg * 8) * P_SZ + (prow0 + m * 16);
      #pragma unroll
      for (int i = 0; i < 8; ++i) {
        float xv = xp[(size_t)i * P_SZ];
        unsigned short h = f2bf(xv);
        ah[m][i] = (short)h;
        al[m][i] = (short)f2bf(xv - bf2f(h));
      }
    }
    short8 bh[4], bl[4];
    #pragma unroll
    for (int n = 0; n < 4; ++n) {
      const float* wr = W + (size_t)(wo * 64 + n * 16 + lr) * CIN + kc + lg * 8;
      #pragma unroll
      for (int i = 0; i < 8; ++i) {
        float wv = wr[i];
        unsigned short h = f2bf(wv);
        bh[n][i] = (short)h;
        bl[n][i] = (short)f2bf(wv - bf2f(h));
      }
    }
    #pragma unroll
    for (int m = 0; m < 2; ++m)
      #pragma unroll
      for (int n = 0; n < 4; ++n) {
        acc[m][n] = __builtin_amdgcn_mfma_f32_16x16x32_bf16(ah[m], bh[n], acc[m][n], 0, 0, 0);
        acc[m][n] = __builtin_amdgcn_mfma_f32_16x16x32_bf16(ah[m], bl[n], acc[m][n], 0, 0, 0);
        acc[m][n] = __builtin_amdgcn_mfma_f32_16x16x32_bf16(al[m], bh[n], acc[m][n], 0, 0, 0);
      }
  }

  #pragma unroll
  for (int n = 0; n < 4; ++n) {
    const int o = wo * 64 + n * 16 + lr;
    const float bv = bias[o];
    #pragma unroll
    for (int m = 0; m < 2; ++m) {
      #pragma unroll
      for (int j = 0; j < 4; ++j) {
        const int p = p0 + wp * 32 + m * 16 + lg * 4 + j;
        const int oswz = o ^ ((p & 7) << 3);
        out[((size_t)b * P_SZ + p) * CH + oswz] = (_Float16)(acc[m][n][j] + bv);
      }
    }
  }
}

// ---------------- Fused flash attention, LDS-staged K/V, pipelined ----------------
// QBLK=64 queries/block, KVB=32 keys/tile, 8 waves = 4 q-groups x 2 (key-half / ch-half).
// K,V double-buffered in LDS via global_load_lds; stage for t+1 issued in phase B of t,
// waited (vmcnt) at end of phase C -> full-iteration latency cover. Raw s_barrier with
// counted waits so stages stay in flight across barriers.
__global__ __launch_bounds__(512, 2) void attn_kernel(
    const _Float16* __restrict__ Qg, const _Float16* __restrict__ Kg,
    const _Float16* __restrict__ Vg, float* __restrict__ Og) {
  __shared__ char K_lds[2][KVB * 512];       // [key][256ch], rows pre-swizzled
  __shared__ char V_lds[2][CV * KVB * 2];    // [ch][32key], 64B rows (conflict-free)
  __shared__ float S_lds[QBLK][36];
  __shared__ _Float16 P_lds[QBLK][KVB];
  __shared__ float alpha_lds[QBLK];
  __shared__ float lsum_lds[QBLK];

  const int b = blockIdx.x & 3;              // batch = blockIdx%4 -> same batch per XCD
  const int q0 = (blockIdx.x >> 2) * QBLK;
  const int tid = threadIdx.x;
  const int w = tid >> 6, l = tid & 63;
  const int lr = l & 15, lg = l >> 4;
  const int wq = w >> 1;       // 4 q-groups of 16 rows
  const int kc = w & 1;        // QK: 16-key half; PV: 256-ch half

  const char* Kb = (const char*)(Kg + (size_t)b * P_SZ * CH);
  const char* Vb = (const char*)(Vg + (size_t)b * CV * P_SZ);

  // Q fragments (global layout is chunk-swizzled by row)
  half8 qf[8];
  {
    const char* qrow = (const char*)(Qg + ((size_t)b * P_SZ + q0 + wq * 16 + lr) * CH);
    #pragma unroll
    for (int c = 0; c < 8; ++c)
      qf[c] = *(const half8*)(qrow + ((c * 64 + lg * 16) ^ ((lr & 7) << 4)));
  }

  f4 acc[16];
  #pragma unroll
  for (int n = 0; n < 16; ++n) acc[n] = (f4){0.f, 0.f, 0.f, 0.f};

  // prologue: stage tile 0
  {
    #pragma unroll
    for (int p = 0; p < 2; ++p)
      gload16(Kb + p * 8192 + tid * 16, &K_lds[0][p * 8192 + w * 1024]);
    #pragma unroll
    for (int p = 0; p < 4; ++p) {
      const int e = p * 512 + tid;
      gload16(Vb + (size_t)(e >> 2) * (P_SZ * 2) + (e & 3) * 16,
              &V_lds[0][p * 8192 + w * 1024]);
    }
  }
  asm volatile("s_waitcnt vmcnt(0)" ::: "memory");
  __builtin_amdgcn_s_barrier();
  __builtin_amdgcn_sched_barrier(0);

  float mrow = -1e30f, lsum = 0.f;
  const int r = tid >> 3;        // softmax row (64 rows x 8 lanes)
  const int rl = tid & 7;
  int cur = 0;

  #pragma unroll 1
  for (int t = 0; t < NT; ++t) {
    // ---- A: QK^T for this tile ----
    {
      const char* kb = K_lds[cur];
      const int key = kc * 16 + lr;
      f4 s = (f4){0.f, 0.f, 0.f, 0.f};
      #pragma unroll
      for (int c = 0; c < 8; ++c) {
        half8 bf = *(const half8*)(kb + key * 512 + ((c * 64 + lg * 16) ^ ((lr & 7) << 4)));
        s = __builtin_amdgcn_mfma_f32_16x16x32_f16(qf[c], bf, s, 0, 0, 0);
      }
      #pragma unroll
      for (int j = 0; j < 4; ++j)
        S_lds[wq * 16 + lg * 4 + j][kc * 16 + lr] = s[j];
    }
    asm volatile("s_waitcnt lgkmcnt(0)" ::: "memory");
    __builtin_amdgcn_s_barrier();
    __builtin_amdgcn_sched_barrier(0);

    // ---- B: issue stage for t+1, then softmax ----
    if (t + 1 < NT) {
      const int nxt = cur ^ 1;
      const char* kg = Kb + (size_t)(t + 1) * KVB * 512;
      #pragma unroll
      for (int p = 0; p < 2; ++p)
        gload16(kg + p * 8192 + tid * 16, &K_lds[nxt][p * 8192 + w * 1024]);
      #pragma unroll
      for (int p = 0; p < 4; ++p) {
        const int e = p * 512 + tid;
        gload16(Vb + (size_t)(e >> 2) * (P_SZ * 2) + (size_t)(t + 1) * KVB * 2 + (e & 3) * 16,
                &V_lds[nxt][p * 8192 + w * 1024]);
      }
    }
    {
      f4 sv = *(const f4*)&S_lds[r][rl * 4];
      float tmax = fmaxf(fmaxf(sv[0], sv[1]), fmaxf(sv[2], sv[3]));
      #pragma unroll
      for (int off = 1; off < 8; off <<= 1) tmax = fmaxf(tmax, __shfl_xor(tmax, off));
      const float mnew = fmaxf(mrow, tmax);
      const float alpha = __expf(mrow - mnew);
      const float e0 = __expf(sv[0] - mnew), e1 = __expf(sv[1] - mnew);
      const float e2 = __expf(sv[2] - mnew), e3 = __expf(sv[3] - mnew);
      float ssum = (e0 + e1) + (e2 + e3);
      #pragma unroll
      for (int off = 1; off < 8; off <<= 1) ssum += __shfl_xor(ssum, off);
      lsum = lsum * alpha + ssum;
      mrow = mnew;
      half4v pv;
      pv[0] = (_Float16)e0; pv[1] = (_Float16)e1;
      pv[2] = (_Float16)e2; pv[3] = (_Float16)e3;
      *(half4v*)&P_lds[r][rl * 4] = pv;
      if (rl == 0) alpha_lds[r] = alpha;
    }
    asm volatile("s_waitcnt lgkmcnt(0)" ::: "memory");
    __builtin_amdgcn_s_barrier();
    __builtin_amdgcn_sched_barrier(0);

    // ---- C: PV ----
    {
      float aj[4];
      #pragma unroll
      for (int j = 0; j < 4; ++j) aj[j] = alpha_lds[wq * 16 + lg * 4 + j];
      #pragma unroll
      for (int n = 0; n < 16; ++n) {
        acc[n][0] *= aj[0]; acc[n][1] *= aj[1];
        acc[n][2] *= aj[2]; acc[n][3] *= aj[3];
      }
      half8 af = *(const half8*)&P_lds[wq * 16 + lr][lg * 8];
      const char* vb = V_lds[cur];
      #pragma unroll
      for (int n = 0; n < 16; ++n) {
        const int ch = kc * 256 + n * 16 + lr;
        half8 bv = *(const half8*)(vb + ch * 64 + lg * 16);
        acc[n] = __builtin_amdgcn_mfma_f32_16x16x32_f16(af, bv, acc[n], 0, 0, 0);
      }
    }
    asm volatile("s_waitcnt vmcnt(0)" ::: "memory");   // own t+1 stage arrived
    __builtin_amdgcn_s_barrier();
    __builtin_amdgcn_sched_barrier(0);
    cur ^= 1;
  }

  if (rl == 0) lsum_lds[r] = lsum;
  __syncthreads();
  float linv[4];
  #pragma unroll
  for (int j = 0; j < 4; ++j) linv[j] = 1.f / lsum_lds[wq * 16 + lg * 4 + j];
  #pragma unroll
  for (int n = 0; n < 16; ++n) {
    f4 o;
    o[0] = acc[n][0] * linv[0]; o[1] = acc[n][1] * linv[1];
    o[2] = acc[n][2] * linv[2]; o[3] = acc[n][3] * linv[3];
    const int ch = kc * 256 + n * 16 + lr;
    float* op = Og + ((size_t)b * CV + ch) * P_SZ + q0 + wq * 16 + lg * 4;
    *(f4*)op = o;
  }
}

extern "C" void kernel_launch(void* const* d_in, const int* in_sizes, int n_in,
                              void* d_out, int out_size, void* d_ws, size_t ws_size,
                              hipStream_t stream) {
  const float* x  = (const float*)d_in[0];   // query_features  [4,512,64,64]
  const float* f  = (const float*)d_in[1];   // reference_features [4,512,64,64]
  const float* Wq = (const float*)d_in[2];   // [256,512]
  const float* bq = (const float*)d_in[3];   // [256]
  const float* Wk = (const float*)d_in[4];   // [256,512]
  const float* bk = (const float*)d_in[5];   // [256]
  float* out = (float*)d_out;

  char* ws = (char*)d_ws;
  _Float16* Qf = (_Float16*)ws;                               // [4][4096][256] fp16: 8 MB
  _Float16* Kf = (_Float16*)(ws + (size_t)8 * 1024 * 1024);   // [4][4096][256]: 8 MB
  _Float16* Vf = (_Float16*)(ws + (size_t)16 * 1024 * 1024);  // [4][512][4096]: 16 MB

  vconv_kernel<<<dim3(8192), dim3(256), 0, stream>>>(f, Vf);
  proj_kernel<<<dim3(64, 4, 2), dim3(512), 0, stream>>>(x, Wq, bq, f, Wk, bk, Qf, Kf);
  attn_kernel<<<dim3(256), dim3(512), 0, stream>>>(Qf, Kf, Vf, out);
}